// Round 14
// baseline (2246.346 us; speedup 1.0000x reference)
//
#include <hip/hip_runtime.h>
#include <stdint.h>

#define B_TRAJ  4096
#define H_DIM   100
#define T_STEPS 100
#define ROWS    8
#define NBLK    512
#define THREADS 1024

typedef float    f32x4  __attribute__((ext_vector_type(4)));
typedef __bf16   bf16x8 __attribute__((ext_vector_type(8)));

// ---- packed-weight layout in d_ws (BYTE offsets) ----
#define OB_P0F   0         // u16, 65536 B
#define OB_P1F   65536     // fp8 W1^T
#define OB_P2F   131072
#define OB_P3F   196608
#define OB_P1B   262144    // fp8 W1
#define OB_P2B   327680
#define OB_P3B   393216
#define OB_P0B   458752    // fp8 W0 cols, [8][128][32], 32768 B
#define OB_W4F8  491520    // fp8 W4 x128, 256 B
#define OB_KEYS  491776    // u32[200]
#define PACK_TOTAL 459008
#define PACK_GRID ((PACK_TOTAL + 255) / 256)

#define WSCALE   32.0f
#define INV_WS   0.03125f        // 1/32
#define INV_ZS   2.44140625e-4f  // 1/4096

__device__ __forceinline__ uint16_t f2bf(float f) {
  uint32_t u = __float_as_uint(f);
  uint32_t r = u + 0x7FFFu + ((u >> 16) & 1u);   // RNE
  return (uint16_t)(r >> 16);
}
__device__ __forceinline__ uint8_t f2e4m3(float v) {
  int pk = __builtin_amdgcn_cvt_pk_fp8_f32(v, 0.0f, 0, false);
  return (uint8_t)(pk & 0xFF);
}
__device__ __forceinline__ uint32_t rotl32(uint32_t v, int d) {
  return (v << d) | (v >> (32 - d));
}

// JAX Threefry-2x32, 20 rounds, exact key schedule.
__device__ __forceinline__ void threefry2x32(uint32_t k0, uint32_t k1,
                                             uint32_t x0, uint32_t x1,
                                             uint32_t& o0, uint32_t& o1) {
  const uint32_t k2 = k0 ^ k1 ^ 0x1BD11BDAu;
  x0 += k0; x1 += k1;
  x0 += x1; x1 = rotl32(x1, 13); x1 ^= x0;
  x0 += x1; x1 = rotl32(x1, 15); x1 ^= x0;
  x0 += x1; x1 = rotl32(x1, 26); x1 ^= x0;
  x0 += x1; x1 = rotl32(x1,  6); x1 ^= x0;
  x0 += k1; x1 += k2 + 1u;
  x0 += x1; x1 = rotl32(x1, 17); x1 ^= x0;
  x0 += x1; x1 = rotl32(x1, 29); x1 ^= x0;
  x0 += x1; x1 = rotl32(x1, 16); x1 ^= x0;
  x0 += x1; x1 = rotl32(x1, 24); x1 ^= x0;
  x0 += k2; x1 += k0 + 2u;
  x0 += x1; x1 = rotl32(x1, 13); x1 ^= x0;
  x0 += x1; x1 = rotl32(x1, 15); x1 ^= x0;
  x0 += x1; x1 = rotl32(x1, 26); x1 ^= x0;
  x0 += x1; x1 = rotl32(x1,  6); x1 ^= x0;
  x0 += k0; x1 += k1 + 3u;
  x0 += x1; x1 = rotl32(x1, 17); x1 ^= x0;
  x0 += x1; x1 = rotl32(x1, 29); x1 ^= x0;
  x0 += x1; x1 = rotl32(x1, 16); x1 ^= x0;
  x0 += x1; x1 = rotl32(x1, 24); x1 ^= x0;
  x0 += k1; x1 += k2 + 4u;
  x0 += x1; x1 = rotl32(x1, 13); x1 ^= x0;
  x0 += x1; x1 = rotl32(x1, 15); x1 ^= x0;
  x0 += x1; x1 = rotl32(x1, 26); x1 ^= x0;
  x0 += x1; x1 = rotl32(x1,  6); x1 ^= x0;
  x0 += k2; x1 += k0 + 5u;
  o0 = x0; o1 = x1;
}

// XLA ErfInv32 (Giles); w via fast hardware log (v_log_f32).
__device__ __forceinline__ float erfinv_f32(float x) {
  float w = -__logf(fmaf(-x, x, 1.0f));
  float p;
  if (w < 5.0f) {
    w = w - 2.5f;
    p = 2.81022636e-08f;
    p = fmaf(p, w, 3.43273939e-07f);
    p = fmaf(p, w, -3.5233877e-06f);
    p = fmaf(p, w, -4.39150654e-06f);
    p = fmaf(p, w, 0.00021858087f);
    p = fmaf(p, w, -0.00125372503f);
    p = fmaf(p, w, -0.00417768164f);
    p = fmaf(p, w, 0.246640727f);
    p = fmaf(p, w, 1.50140941f);
  } else {
    w = sqrtf(w) - 3.0f;
    p = -0.000200214257f;
    p = fmaf(p, w, 0.000100950558f);
    p = fmaf(p, w, 0.00134934322f);
    p = fmaf(p, w, -0.00367342844f);
    p = fmaf(p, w, 0.00573950773f);
    p = fmaf(p, w, -0.0076224613f);
    p = fmaf(p, w, 0.00943887047f);
    p = fmaf(p, w, 1.00167406f);
    p = fmaf(p, w, 2.83297682f);
  }
  return p * x;
}

// ---------------- weight packing + key chain (once per launch) ----------------
__global__ __launch_bounds__(256) void pack_kernel(
    const float* __restrict__ W0, const float* __restrict__ W1,
    const float* __restrict__ W2, const float* __restrict__ W3,
    const float* __restrict__ W4, uint8_t* __restrict__ P) {
  const int i = blockIdx.x * 256 + threadIdx.x;
  if (i == 0) {
    uint32_t* K = (uint32_t*)(P + OB_KEYS);
    uint32_t c0 = 0u, c1 = 42u;
    for (int s = 0; s < T_STEPS; ++s) {
      uint32_t a0_, a1_, n0, n1;
      threefry2x32(c0, c1, 0u, 0u, a0_, a1_);
      threefry2x32(c0, c1, 0u, 1u, n0, n1);
      K[2 * s] = a0_; K[2 * s + 1] = a1_;
      c0 = n0; c1 = n1;
    }
  }
  if (i >= PACK_TOTAL) return;

  if (i < 32768) {                  // P0F bf16: [4][256][32], W0[n][k], K pad 128
    const int e = i;
    const int kk = e & 31, n = (e >> 5) & 255, kt = e >> 13;
    const int k = kt * 32 + kk;
    const float v = (k < 101) ? W0[n * 101 + k] : 0.0f;
    ((uint16_t*)(P + OB_P0F))[e] = f2bf(v);
    return;
  }
  int j = i - 32768;
  if (j < 393216) {                 // six fp8 packs, x32
    const int pk = j >> 16;
    const int e = j & 65535;
    const int kk = e & 31, n = (e >> 5) & 255, kt = e >> 13;
    const int k = kt * 32 + kk;
    float v;
    switch (pk) {
      case 0: v = W1[n * 256 + k]; break;           // P1F = W1^T
      case 1: v = W2[n * 256 + k]; break;
      case 2: v = W3[n * 256 + k]; break;
      case 3: v = W1[k * 256 + n]; break;           // P1B = W1
      case 4: v = W2[k * 256 + n]; break;
      default: v = W3[k * 256 + n]; break;
    }
    P[OB_P1F + j] = f2e4m3(v * WSCALE);
    return;
  }
  j -= 393216;
  if (j < 32768) {                  // P0B fp8: [8][128][32], W0[k][1+n], x32
    const int kk = j & 31, n = (j >> 5) & 127, kt = j >> 12;
    const int k = kt * 32 + kk;
    const float v = (n < 100) ? W0[k * 101 + 1 + n] : 0.0f;
    P[OB_P0B + j] = f2e4m3(v * WSCALE);
    return;
  }
  j -= 32768;                       // W4 fp8 x128 (dp4 scale)
  P[OB_W4F8 + j] = f2e4m3(W4[j] * 128.0f);
}

// ---------------- LDS (diet: 9-row MFMA arrays, shared zero row 8) ----------
// A-fragment loads clamp row16 -> min(row16, 8); row 8 stays all-zero (all
// stores are g<2 => rows 0-7). dpB aliases act4 (act4 dead after P4).
// Total ~27.2 KB/block => 2 blocks fit under a 64 KB per-CU LDS pool.
struct SmemT {
  uint16_t actI[9][136];      // MLP input bf16, K padded to 128
  uint8_t  act1[9][264];      // fp8 activations (scale 1)
  uint8_t  act2[9][264];
  uint8_t  act3[9][264];
  uint8_t  dp4[9][264];       // fp8 dp4 (scale 128), built in P3 epilogue
  uint8_t  dpA[9][264];
  uint8_t  act4_dpB[9][264];  // act4 through P4, then dpB (P5 out, P6 in)
  float x_s[ROWS * H_DIM];
  float z_s[ROWS * H_DIM];
  float dw_s[ROWS * H_DIM];
  float y_s[ROWS];
  uint32_t keyA[T_STEPS], keyB[T_STEPS];
};

// ---------------- fp8 GEMM phase helpers (1 col-tile per wave) -------------
// D[r][c]: r=(lane>>4)*4+reg, c=lane&15. Rows 8-15 pad -> A row = min(row16,8).

__device__ __forceinline__ void gemm_fwd_f8(const uint8_t (*in)[264],
                                            const uint8_t* __restrict__ Pm,
                                            const float* __restrict__ bias,
                                            uint8_t (*outb)[264],
                                            int wave, int lane) {
  const int row16 = lane & 15, g = lane >> 4;
  const int c = row16 + 16 * wave;
  const uint8_t* arow = in[(row16 < 8) ? row16 : 8];
  long bfr[8], afr[8];
#pragma unroll
  for (int kt = 0; kt < 8; ++kt)
    bfr[kt] = *reinterpret_cast<const long*>(Pm + (kt * 256 + c) * 32 + g * 8);
#pragma unroll
  for (int kt = 0; kt < 8; ++kt)
    afr[kt] = *reinterpret_cast<const long*>(arow + kt * 32 + g * 8);
  f32x4 acc = {0.f, 0.f, 0.f, 0.f};
#pragma unroll
  for (int kt = 0; kt < 8; ++kt)
    acc = __builtin_amdgcn_mfma_f32_16x16x32_fp8_fp8(afr[kt], bfr[kt], acc, 0, 0, 0);
  if (g < 2) {
    const float bv = bias[c];
    const float h0 = fmaxf(fmaf(acc[0], INV_WS, bv), 0.0f);
    const float h1 = fmaxf(fmaf(acc[1], INV_WS, bv), 0.0f);
    const float h2 = fmaxf(fmaf(acc[2], INV_WS, bv), 0.0f);
    const float h3 = fmaxf(fmaf(acc[3], INV_WS, bv), 0.0f);
    const int p01 = __builtin_amdgcn_cvt_pk_fp8_f32(h0, h1, 0, false);
    const int p23 = __builtin_amdgcn_cvt_pk_fp8_f32(h2, h3, 0, false);
    outb[g * 4 + 0][c] = (uint8_t)(p01 & 0xFF);
    outb[g * 4 + 1][c] = (uint8_t)((p01 >> 8) & 0xFF);
    outb[g * 4 + 2][c] = (uint8_t)(p23 & 0xFF);
    outb[g * 4 + 3][c] = (uint8_t)((p23 >> 8) & 0xFF);
  }
}

// P3 variant: also emits dp4 = (h>0 ? W4f8 : 0) from registers.
__device__ __forceinline__ void gemm_fwd3_f8(const uint8_t (*in)[264],
                                             const uint8_t* __restrict__ Pm,
                                             const float* __restrict__ bias,
                                             const uint8_t* __restrict__ W4F8,
                                             uint8_t (*outb)[264],
                                             uint8_t (*dp4b)[264],
                                             int wave, int lane) {
  const int row16 = lane & 15, g = lane >> 4;
  const int c = row16 + 16 * wave;
  const uint8_t* arow = in[(row16 < 8) ? row16 : 8];
  long bfr[8], afr[8];
#pragma unroll
  for (int kt = 0; kt < 8; ++kt)
    bfr[kt] = *reinterpret_cast<const long*>(Pm + (kt * 256 + c) * 32 + g * 8);
#pragma unroll
  for (int kt = 0; kt < 8; ++kt)
    afr[kt] = *reinterpret_cast<const long*>(arow + kt * 32 + g * 8);
  f32x4 acc = {0.f, 0.f, 0.f, 0.f};
#pragma unroll
  for (int kt = 0; kt < 8; ++kt)
    acc = __builtin_amdgcn_mfma_f32_16x16x32_fp8_fp8(afr[kt], bfr[kt], acc, 0, 0, 0);
  if (g < 2) {
    const float bv = bias[c];
    const uint8_t w4b = W4F8[c];
    const float h0 = fmaxf(fmaf(acc[0], INV_WS, bv), 0.0f);
    const float h1 = fmaxf(fmaf(acc[1], INV_WS, bv), 0.0f);
    const float h2 = fmaxf(fmaf(acc[2], INV_WS, bv), 0.0f);
    const float h3 = fmaxf(fmaf(acc[3], INV_WS, bv), 0.0f);
    const int p01 = __builtin_amdgcn_cvt_pk_fp8_f32(h0, h1, 0, false);
    const int p23 = __builtin_amdgcn_cvt_pk_fp8_f32(h2, h3, 0, false);
    outb[g * 4 + 0][c] = (uint8_t)(p01 & 0xFF);
    outb[g * 4 + 1][c] = (uint8_t)((p01 >> 8) & 0xFF);
    outb[g * 4 + 2][c] = (uint8_t)(p23 & 0xFF);
    outb[g * 4 + 3][c] = (uint8_t)((p23 >> 8) & 0xFF);
    dp4b[g * 4 + 0][c] = (h0 > 0.0f) ? w4b : (uint8_t)0;
    dp4b[g * 4 + 1][c] = (h1 > 0.0f) ? w4b : (uint8_t)0;
    dp4b[g * 4 + 2][c] = (h2 > 0.0f) ? w4b : (uint8_t)0;
    dp4b[g * 4 + 3][c] = (h3 > 0.0f) ? w4b : (uint8_t)0;
  }
}

__device__ __forceinline__ void gemm_bwd_f8(const uint8_t (*in)[264],
                                            const uint8_t* __restrict__ Pm,
                                            const uint8_t (*mact)[264],
                                            uint8_t (*outb)[264],
                                            int wave, int lane) {
  const int row16 = lane & 15, g = lane >> 4;
  const int c = row16 + 16 * wave;
  const uint8_t* arow = in[(row16 < 8) ? row16 : 8];
  long bfr[8], afr[8];
#pragma unroll
  for (int kt = 0; kt < 8; ++kt)
    bfr[kt] = *reinterpret_cast<const long*>(Pm + (kt * 256 + c) * 32 + g * 8);
#pragma unroll
  for (int kt = 0; kt < 8; ++kt)
    afr[kt] = *reinterpret_cast<const long*>(arow + kt * 32 + g * 8);
  f32x4 acc = {0.f, 0.f, 0.f, 0.f};
#pragma unroll
  for (int kt = 0; kt < 8; ++kt)
    acc = __builtin_amdgcn_mfma_f32_16x16x32_fp8_fp8(afr[kt], bfr[kt], acc, 0, 0, 0);
  if (g < 2) {
    const int p01 = __builtin_amdgcn_cvt_pk_fp8_f32(acc[0] * INV_WS, acc[1] * INV_WS, 0, false);
    const int p23 = __builtin_amdgcn_cvt_pk_fp8_f32(acc[2] * INV_WS, acc[3] * INV_WS, 0, false);
    outb[g * 4 + 0][c] = mact[g * 4 + 0][c] ? (uint8_t)(p01 & 0xFF) : (uint8_t)0;
    outb[g * 4 + 1][c] = mact[g * 4 + 1][c] ? (uint8_t)((p01 >> 8) & 0xFF) : (uint8_t)0;
    outb[g * 4 + 2][c] = mact[g * 4 + 2][c] ? (uint8_t)(p23 & 0xFF) : (uint8_t)0;
    outb[g * 4 + 3][c] = mact[g * 4 + 3][c] ? (uint8_t)((p23 >> 8) & 0xFF) : (uint8_t)0;
  }
}

// ---------------- MLP fwd + VJP eval (NOINLINE: hard codegen boundary) ------
// Keep outlined (R7/R8 lesson: inlining -> load hoisting across barriers ->
// VGPR blowout -> scratch spill -> L2 pollution -> 10.5 GB HBM re-fetch).
__device__ __attribute__((noinline)) void mlp_eval(
    SmemT& sm, const uint8_t* __restrict__ P,
    const float* __restrict__ b0, const float* __restrict__ b1,
    const float* __restrict__ b2, const float* __restrict__ b3,
    const float* __restrict__ W4, const float* __restrict__ b4,
    float* __restrict__ ys_out, int row0, int next_s, int blk, float sqdt) {
  const int tid = threadIdx.x;
  const int wave = tid >> 6, lane = tid & 63;
  const int row16 = lane & 15, g = lane >> 4;
  const int c = row16 + 16 * wave;

  // P0: L0 fwd, bf16 MFMA
  {
    const uint16_t* P0F = (const uint16_t*)(P + OB_P0F);
    const uint16_t* arow = sm.actI[(row16 < 8) ? row16 : 8];
    bf16x8 bfr[4], afr[4];
#pragma unroll
    for (int kt = 0; kt < 4; ++kt)
      bfr[kt] = *reinterpret_cast<const bf16x8*>(&P0F[(kt * 256 + c) * 32 + g * 8]);
#pragma unroll
    for (int kt = 0; kt < 4; ++kt)
      afr[kt] = *reinterpret_cast<const bf16x8*>(arow + kt * 32 + g * 8);
    f32x4 acc = {0.f, 0.f, 0.f, 0.f};
#pragma unroll
    for (int kt = 0; kt < 4; ++kt)
      acc = __builtin_amdgcn_mfma_f32_16x16x32_bf16(afr[kt], bfr[kt], acc, 0, 0, 0);
    if (g < 2) {
      const float bv = b0[c];
      const float h0 = fmaxf(acc[0] + bv, 0.0f), h1 = fmaxf(acc[1] + bv, 0.0f);
      const float h2 = fmaxf(acc[2] + bv, 0.0f), h3 = fmaxf(acc[3] + bv, 0.0f);
      const int p01 = __builtin_amdgcn_cvt_pk_fp8_f32(h0, h1, 0, false);
      const int p23 = __builtin_amdgcn_cvt_pk_fp8_f32(h2, h3, 0, false);
      sm.act1[g * 4 + 0][c] = (uint8_t)(p01 & 0xFF);
      sm.act1[g * 4 + 1][c] = (uint8_t)((p01 >> 8) & 0xFF);
      sm.act1[g * 4 + 2][c] = (uint8_t)(p23 & 0xFF);
      sm.act1[g * 4 + 3][c] = (uint8_t)((p23 >> 8) & 0xFF);
    }
  }
  __syncthreads();

  // P1-P3: fwd fp8 (P3 also emits dp4; act4 lives in act4_dpB)
  gemm_fwd_f8(sm.act1, P + OB_P1F, b1, sm.act2, wave, lane);
  __syncthreads();
  gemm_fwd_f8(sm.act2, P + OB_P2F, b2, sm.act3, wave, lane);
  __syncthreads();
  gemm_fwd3_f8(sm.act3, P + OB_P3F, b3, P + OB_W4F8, sm.act4_dpB, sm.dp4, wave, lane);
  __syncthreads();

  // P4: y-reduction (waves 0-7 own rows 0-7, act4 in act4_dpB) + bwd3 (A=dp4)
  if (wave < ROWS) {
    const uint32_t aw = *reinterpret_cast<const uint32_t*>(&sm.act4_dpB[wave][lane * 4]);
    float sy = __builtin_amdgcn_cvt_f32_fp8(aw, 0) * W4[lane * 4 + 0]
             + __builtin_amdgcn_cvt_f32_fp8(aw, 1) * W4[lane * 4 + 1]
             + __builtin_amdgcn_cvt_f32_fp8(aw, 2) * W4[lane * 4 + 2]
             + __builtin_amdgcn_cvt_f32_fp8(aw, 3) * W4[lane * 4 + 3];
#pragma unroll
    for (int off = 32; off >= 1; off >>= 1) sy += __shfl_xor(sy, off, 64);
    if (lane == 0) {
      const float yv = sy + b4[0];
      sm.y_s[wave] = yv;
      if (ys_out) ys_out[row0 + wave] = yv;
    }
  }
  gemm_bwd_f8(sm.dp4, P + OB_P3B, sm.act3, sm.dpA, wave, lane);
  __syncthreads();

  // P5: bwd2 (out = dpB alias of act4) ; P6: bwd1
  gemm_bwd_f8(sm.dpA, P + OB_P2B, sm.act2, sm.act4_dpB, wave, lane);
  __syncthreads();
  gemm_bwd_f8(sm.act4_dpB, P + OB_P1B, sm.act1, sm.dpA, wave, lane);
  __syncthreads();

  // P7: bwd0 on waves 0-7 (z = acc/4096); waves 8-15 next-step PRNG
  if (wave < 8) {
    const uint8_t* Pm = P + OB_P0B;
    const uint8_t* arow = sm.dpA[(row16 < 8) ? row16 : 8];
    long bfr[8], afr[8];
#pragma unroll
    for (int kt = 0; kt < 8; ++kt)
      bfr[kt] = *reinterpret_cast<const long*>(Pm + (kt * 128 + c) * 32 + g * 8);
#pragma unroll
    for (int kt = 0; kt < 8; ++kt)
      afr[kt] = *reinterpret_cast<const long*>(arow + kt * 32 + g * 8);
    f32x4 acc = {0.f, 0.f, 0.f, 0.f};
#pragma unroll
    for (int kt = 0; kt < 8; ++kt)
      acc = __builtin_amdgcn_mfma_f32_16x16x32_fp8_fp8(afr[kt], bfr[kt], acc, 0, 0, 0);
    if (g < 2 && c < H_DIM) {
#pragma unroll
      for (int reg = 0; reg < 4; ++reg)
        sm.z_s[(g * 4 + reg) * H_DIM + c] = acc[reg] * INV_ZS;
    }
  } else if (next_s >= 0) {
    const uint32_t ka = sm.keyA[next_s], kb = sm.keyB[next_s];
    for (int e = tid - 512; e < ROWS * H_DIM; e += 512) {
      const uint32_t f = (uint32_t)(blk * (ROWS * H_DIM) + e);
      uint32_t o0, o1;
      threefry2x32(ka, kb, 0u, f, o0, o1);
      const uint32_t bits = o0 ^ o1;
      const float fr = __uint_as_float((bits >> 9) | 0x3F800000u) - 1.0f;
      const float minv = -0.99999994f;  // nextafter(-1, 0)
      const float u = fmaxf(fr * 2.0f + minv, minv);
      const float n = 1.41421354f * erfinv_f32(u);
      sm.dw_s[e] = n * sqdt;
    }
  }
  __syncthreads();
}

// ---------------- main kernel ----------------
// 512 blocks x 1024 threads, ROWS=8, LDS ~27 KB: test whether 2 blocks/CU
// become co-resident once 2x LDS fits a 64 KB pool (R13 failed at 89 KB).
__global__ __launch_bounds__(THREADS, 4) void fbsde_kernel(
    const float* __restrict__ x0, const float* __restrict__ t0p,
    const float* __restrict__ dtp,
    const float* __restrict__ b0, const float* __restrict__ b1,
    const float* __restrict__ b2, const float* __restrict__ b3,
    const float* __restrict__ W4, const float* __restrict__ b4,
    const uint8_t* __restrict__ P, float* __restrict__ out) {
  __shared__ __align__(16) SmemT sm;

  const int tid = threadIdx.x;
  const int wave = tid >> 6, lane = tid & 63;
  const int blk = blockIdx.x;
  const int row0 = blk * ROWS;

  // ---- init ----
  if (tid < T_STEPS) {
    const uint32_t* K = (const uint32_t*)(P + OB_KEYS);
    sm.keyA[tid] = K[2 * tid];
    sm.keyB[tid] = K[2 * tid + 1];
  }
  for (int e = tid; e < ROWS * H_DIM; e += THREADS)
    sm.x_s[e] = x0[row0 * H_DIM + e];
  // actI: rows 0-7 = [t,x,pad], row 8 = zero (shared MFMA pad row)
  for (int e = tid; e < 9 * 136; e += THREADS) {
    const int r = e / 136, cc = e - r * 136;
    uint16_t v = 0;
    if (r < ROWS && cc >= 1 && cc <= H_DIM)
      v = f2bf(x0[(row0 + r) * H_DIM + cc - 1]);
    sm.actI[r][cc] = v;
  }
  // zero the 6 contiguous u8[9][264] arrays (pad row 8 must stay 0)
  {
    uint32_t* pz = (uint32_t*)&sm.act1[0][0];
    for (int e = tid; e < 6 * 9 * 264 / 4; e += THREADS) pz[e] = 0u;
  }
  const float t0v = t0p[0];
  const float dtv = dtp[0];
  const float sqdt = sqrtf(dtv);
  __syncthreads();

  float* const out_xfin = out;                                  // (B,H)
  float* const out_yfin = out + 409600;                         // (B,1)
  float* const out_zfin = out + 413696;                         // (B,H)
  float* const out_xs   = out + 823296;                         // (T,B,H)
  float* const out_yt   = out + 823296 + 40960000;              // (T,B,1)
  float* const out_ys   = out + 823296 + 40960000 + 409600;     // (T,B,1)

  // initial eval at t=0 (no ys write; waves 8-15 generate dW for step 0)
  mlp_eval(sm, P, b0, b1, b2, b3, W4, b4, nullptr, row0, 0, blk, sqdt);

  for (int s = 0; s < T_STEPS; ++s) {
    // ---- SDE phase: y_tilde + x-update + next actI; wave w owns row w ----
    const float tv = t0v + (float)(s + 1) * dtv;
    if (wave < ROWS) {
      const int base = wave * H_DIM;
      const int h0 = lane;                 // < 100 always (lane<64)
      const int h1 = lane + 64;            // valid if < 100
      const float xv0 = sm.x_s[base + h0];
      const float zv0 = sm.z_s[base + h0];
      const float dw0 = sm.dw_s[base + h0];
      float s1 = xv0 * zv0;
      float s2 = zv0 * (0.4f * xv0) * dw0;
      float xv1 = 0.f, dw1 = 0.f;
      if (h1 < H_DIM) {
        xv1 = sm.x_s[base + h1];
        const float zv1 = sm.z_s[base + h1];
        dw1 = sm.dw_s[base + h1];
        s1 += xv1 * zv1;
        s2 += zv1 * (0.4f * xv1) * dw1;
      }
#pragma unroll
      for (int off = 32; off >= 1; off >>= 1) {
        s1 += __shfl_xor(s1, off, 64);
        s2 += __shfl_xor(s2, off, 64);
      }
      if (lane == 0) {
        const float yv = sm.y_s[wave];
        const float phi = 0.05f * (yv - s1);
        out_yt[(size_t)s * B_TRAJ + row0 + wave] = yv + phi * dtv + s2;
        sm.actI[wave][0] = f2bf(tv);
      }
      {
        const float x1 = xv0 + (0.4f * xv0) * dw0;
        sm.x_s[base + h0] = x1;
        sm.actI[wave][1 + h0] = f2bf(x1);
        out_xs[(size_t)s * (B_TRAJ * H_DIM) + (size_t)(row0 + wave) * H_DIM + h0] = x1;
        if (h1 < H_DIM) {
          const float x1b = xv1 + (0.4f * xv1) * dw1;
          sm.x_s[base + h1] = x1b;
          sm.actI[wave][1 + h1] = f2bf(x1b);
          out_xs[(size_t)s * (B_TRAJ * H_DIM) + (size_t)(row0 + wave) * H_DIM + h1] = x1b;
        }
      }
    }
    __syncthreads();

    mlp_eval(sm, P, b0, b1, b2, b3, W4, b4, out_ys + (size_t)s * B_TRAJ,
             row0, (s + 1 < T_STEPS) ? s + 1 : -1, blk, sqdt);
  }

  for (int e = tid; e < ROWS * H_DIM; e += THREADS) {
    out_xfin[(size_t)row0 * H_DIM + e] = sm.x_s[e];
    out_zfin[(size_t)row0 * H_DIM + e] = sm.z_s[e];
  }
  if (tid < ROWS) out_yfin[row0 + tid] = sm.y_s[tid];
}

extern "C" void kernel_launch(void* const* d_in, const int* in_sizes, int n_in,
                              void* d_out, int out_size, void* d_ws, size_t ws_size,
                              hipStream_t stream) {
  (void)in_sizes; (void)n_in; (void)ws_size; (void)out_size;
  const float* x0 = (const float*)d_in[0];
  const float* t0 = (const float*)d_in[1];
  const float* dt = (const float*)d_in[2];
  const float* W0 = (const float*)d_in[4];
  const float* b0 = (const float*)d_in[5];
  const float* W1 = (const float*)d_in[6];
  const float* b1 = (const float*)d_in[7];
  const float* W2 = (const float*)d_in[8];
  const float* b2 = (const float*)d_in[9];
  const float* W3 = (const float*)d_in[10];
  const float* b3 = (const float*)d_in[11];
  const float* W4 = (const float*)d_in[12];
  const float* b4 = (const float*)d_in[13];
  uint8_t* P = (uint8_t*)d_ws;
  float* out = (float*)d_out;

  hipLaunchKernelGGL(pack_kernel, dim3(PACK_GRID), dim3(256), 0, stream,
                     W0, W1, W2, W3, W4, P);
  hipLaunchKernelGGL(fbsde_kernel, dim3(NBLK), dim3(THREADS), 0, stream,
                     x0, t0, dt, b0, b1, b2, b3, W4, b4, P, out);
}

// Round 15
// 1214.344 us; speedup vs baseline: 1.8498x; 1.8498x over previous
//
#include <hip/hip_runtime.h>
#include <stdint.h>

#define B_TRAJ  4096
#define H_DIM   100
#define T_STEPS 100
#define ROWS    16
#define NBLK    256
#define THREADS 1024

typedef float    f32x4  __attribute__((ext_vector_type(4)));
typedef __bf16   bf16x8 __attribute__((ext_vector_type(8)));
typedef uint8_t  u8x8   __attribute__((ext_vector_type(8)));

// ---- packed-weight layout in d_ws (BYTE offsets) ----
// P0F (bf16): [4][256][32] u16 ; fp8 packs: [8][N][32] bytes, idx=(kt*N+n)*32+kk
// weights scaled x32 (W4 for dp4 x128); dp carried at 128x; z = acc/4096.
#define OB_P0F   0         // u16, 65536 B
#define OB_P1F   65536     // fp8 W1^T
#define OB_P2F   131072
#define OB_P3F   196608
#define OB_P1B   262144    // fp8 W1
#define OB_P2B   327680
#define OB_P3B   393216
#define OB_P0B   458752    // fp8 W0 cols, [8][128][32], 32768 B
#define OB_W4F8  491520    // fp8 W4 x128, 256 B
#define OB_KEYS  491776    // u32[200]
#define PACK_TOTAL 459008  // element-threads: 32768 u16 + 393216 + 32768 + 256
#define PACK_GRID ((PACK_TOTAL + 255) / 256)

#define WSCALE   32.0f
#define INV_WS   0.03125f        // 1/32
#define INV_ZS   2.44140625e-4f  // 1/4096

__device__ __forceinline__ uint16_t f2bf(float f) {
  uint32_t u = __float_as_uint(f);
  uint32_t r = u + 0x7FFFu + ((u >> 16) & 1u);   // RNE
  return (uint16_t)(r >> 16);
}
__device__ __forceinline__ uint8_t f2e4m3(float v) {
  int pk = __builtin_amdgcn_cvt_pk_fp8_f32(v, 0.0f, 0, false);
  return (uint8_t)(pk & 0xFF);
}
__device__ __forceinline__ uint32_t rotl32(uint32_t v, int d) {
  return (v << d) | (v >> (32 - d));
}

// JAX Threefry-2x32, 20 rounds, exact key schedule.
__device__ __forceinline__ void threefry2x32(uint32_t k0, uint32_t k1,
                                             uint32_t x0, uint32_t x1,
                                             uint32_t& o0, uint32_t& o1) {
  const uint32_t k2 = k0 ^ k1 ^ 0x1BD11BDAu;
  x0 += k0; x1 += k1;
  x0 += x1; x1 = rotl32(x1, 13); x1 ^= x0;
  x0 += x1; x1 = rotl32(x1, 15); x1 ^= x0;
  x0 += x1; x1 = rotl32(x1, 26); x1 ^= x0;
  x0 += x1; x1 = rotl32(x1,  6); x1 ^= x0;
  x0 += k1; x1 += k2 + 1u;
  x0 += x1; x1 = rotl32(x1, 17); x1 ^= x0;
  x0 += x1; x1 = rotl32(x1, 29); x1 ^= x0;
  x0 += x1; x1 = rotl32(x1, 16); x1 ^= x0;
  x0 += x1; x1 = rotl32(x1, 24); x1 ^= x0;
  x0 += k2; x1 += k0 + 2u;
  x0 += x1; x1 = rotl32(x1, 13); x1 ^= x0;
  x0 += x1; x1 = rotl32(x1, 15); x1 ^= x0;
  x0 += x1; x1 = rotl32(x1, 26); x1 ^= x0;
  x0 += x1; x1 = rotl32(x1,  6); x1 ^= x0;
  x0 += k0; x1 += k1 + 3u;
  x0 += x1; x1 = rotl32(x1, 17); x1 ^= x0;
  x0 += x1; x1 = rotl32(x1, 29); x1 ^= x0;
  x0 += x1; x1 = rotl32(x1, 16); x1 ^= x0;
  x0 += x1; x1 = rotl32(x1, 24); x1 ^= x0;
  x0 += k1; x1 += k2 + 4u;
  x0 += x1; x1 = rotl32(x1, 13); x1 ^= x0;
  x0 += x1; x1 = rotl32(x1, 15); x1 ^= x0;
  x0 += x1; x1 = rotl32(x1, 26); x1 ^= x0;
  x0 += x1; x1 = rotl32(x1,  6); x1 ^= x0;
  x0 += k2; x1 += k0 + 5u;
  o0 = x0; o1 = x1;
}

// XLA ErfInv32 (Giles); w via fast hardware log (v_log_f32).
// w = -log(1 - x^2): fmaf(-x,x,1) preserves the cancellation structure;
// __logf ~1 ulp => dW perturbation ~1e-6 rel, negligible vs 0.124 threshold.
__device__ __forceinline__ float erfinv_f32(float x) {
  float w = -__logf(fmaf(-x, x, 1.0f));
  float p;
  if (w < 5.0f) {
    w = w - 2.5f;
    p = 2.81022636e-08f;
    p = fmaf(p, w, 3.43273939e-07f);
    p = fmaf(p, w, -3.5233877e-06f);
    p = fmaf(p, w, -4.39150654e-06f);
    p = fmaf(p, w, 0.00021858087f);
    p = fmaf(p, w, -0.00125372503f);
    p = fmaf(p, w, -0.00417768164f);
    p = fmaf(p, w, 0.246640727f);
    p = fmaf(p, w, 1.50140941f);
  } else {
    w = sqrtf(w) - 3.0f;
    p = -0.000200214257f;
    p = fmaf(p, w, 0.000100950558f);
    p = fmaf(p, w, 0.00134934322f);
    p = fmaf(p, w, -0.00367342844f);
    p = fmaf(p, w, 0.00573950773f);
    p = fmaf(p, w, -0.0076224613f);
    p = fmaf(p, w, 0.00943887047f);
    p = fmaf(p, w, 1.00167406f);
    p = fmaf(p, w, 2.83297682f);
  }
  return p * x;
}

// ---------------- weight packing + key chain (once per launch) ----------------
__global__ __launch_bounds__(256) void pack_kernel(
    const float* __restrict__ W0, const float* __restrict__ W1,
    const float* __restrict__ W2, const float* __restrict__ W3,
    const float* __restrict__ W4, uint8_t* __restrict__ P) {
  const int i = blockIdx.x * 256 + threadIdx.x;
  if (i == 0) {  // serial key chain: key(42), per step use child0, carry child1
    uint32_t* K = (uint32_t*)(P + OB_KEYS);
    uint32_t c0 = 0u, c1 = 42u;
    for (int s = 0; s < T_STEPS; ++s) {
      uint32_t a0_, a1_, n0, n1;
      threefry2x32(c0, c1, 0u, 0u, a0_, a1_);
      threefry2x32(c0, c1, 0u, 1u, n0, n1);
      K[2 * s] = a0_; K[2 * s + 1] = a1_;
      c0 = n0; c1 = n1;
    }
  }
  if (i >= PACK_TOTAL) return;

  if (i < 32768) {                  // P0F bf16: [4][256][32], W0[n][k], K pad 128
    const int e = i;
    const int kk = e & 31, n = (e >> 5) & 255, kt = e >> 13;
    const int k = kt * 32 + kk;
    const float v = (k < 101) ? W0[n * 101 + k] : 0.0f;
    ((uint16_t*)(P + OB_P0F))[e] = f2bf(v);
    return;
  }
  int j = i - 32768;
  if (j < 393216) {                 // six fp8 packs, x32
    const int pk = j >> 16;         // 0..5
    const int e = j & 65535;
    const int kk = e & 31, n = (e >> 5) & 255, kt = e >> 13;
    const int k = kt * 32 + kk;
    float v;
    switch (pk) {
      case 0: v = W1[n * 256 + k]; break;           // P1F = W1^T
      case 1: v = W2[n * 256 + k]; break;
      case 2: v = W3[n * 256 + k]; break;
      case 3: v = W1[k * 256 + n]; break;           // P1B = W1
      case 4: v = W2[k * 256 + n]; break;
      default: v = W3[k * 256 + n]; break;
    }
    P[OB_P1F + j] = f2e4m3(v * WSCALE);
    return;
  }
  j -= 393216;
  if (j < 32768) {                  // P0B fp8: [8][128][32], W0[k][1+n], x32
    const int kk = j & 31, n = (j >> 5) & 127, kt = j >> 12;
    const int k = kt * 32 + kk;
    const float v = (n < 100) ? W0[k * 101 + 1 + n] : 0.0f;
    P[OB_P0B + j] = f2e4m3(v * WSCALE);
    return;
  }
  j -= 32768;                       // W4 fp8 x128 (dp4 scale)
  P[OB_W4F8 + j] = f2e4m3(W4[j] * 128.0f);
}

// ---------------- LDS ----------------
struct SmemT {
  uint16_t actI[ROWS][136];   // MLP input bf16, K padded to 128
  uint8_t  act1[ROWS][264];   // fp8 activations (scale 1)
  uint8_t  act2[ROWS][264];
  uint8_t  act3[ROWS][264];
  uint8_t  act4[ROWS][264];
  uint8_t  dp4[ROWS][264];    // fp8 dp4 (scale 128), built in P3 epilogue
  uint8_t  dpA[ROWS][264];    // fp8 dp (scale 128)
  uint8_t  dpB[ROWS][264];
  float x_s[ROWS * H_DIM];
  float z_s[ROWS * H_DIM];
  float dw_s[ROWS * H_DIM];
  float y_s[ROWS];
  uint32_t keyA[T_STEPS], keyB[T_STEPS];
};

// ---------------- fp8 GEMM phase helpers (MFMA 16x16x32 fp8_fp8) ----------
// Same (g,e) k-slot packing on A and B -> HW k-permutation cancels (as bf16).
// D[r][c]: r=(lane>>4)*4+reg, c=lane&15.

__device__ __forceinline__ void gemm_fwd_f8(const uint8_t (*in)[264],
                                            const uint8_t* __restrict__ Pm,
                                            const float* __restrict__ bias,
                                            uint8_t (*outb)[264],
                                            int wave, int lane) {
  const int row16 = lane & 15, g = lane >> 4;
  const int c = row16 + 16 * wave;
  long bfr[8], afr[8];
#pragma unroll
  for (int kt = 0; kt < 8; ++kt)
    bfr[kt] = *reinterpret_cast<const long*>(Pm + (kt * 256 + c) * 32 + g * 8);
#pragma unroll
  for (int kt = 0; kt < 8; ++kt)
    afr[kt] = *reinterpret_cast<const long*>(&in[row16][kt * 32 + g * 8]);
  f32x4 acc = {0.f, 0.f, 0.f, 0.f};
#pragma unroll
  for (int kt = 0; kt < 8; ++kt)
    acc = __builtin_amdgcn_mfma_f32_16x16x32_fp8_fp8(afr[kt], bfr[kt], acc, 0, 0, 0);
  const float bv = bias[c];
  const float h0 = fmaxf(fmaf(acc[0], INV_WS, bv), 0.0f);
  const float h1 = fmaxf(fmaf(acc[1], INV_WS, bv), 0.0f);
  const float h2 = fmaxf(fmaf(acc[2], INV_WS, bv), 0.0f);
  const float h3 = fmaxf(fmaf(acc[3], INV_WS, bv), 0.0f);
  const int p01 = __builtin_amdgcn_cvt_pk_fp8_f32(h0, h1, 0, false);
  const int p23 = __builtin_amdgcn_cvt_pk_fp8_f32(h2, h3, 0, false);
  outb[g * 4 + 0][c] = (uint8_t)(p01 & 0xFF);
  outb[g * 4 + 1][c] = (uint8_t)((p01 >> 8) & 0xFF);
  outb[g * 4 + 2][c] = (uint8_t)(p23 & 0xFF);
  outb[g * 4 + 3][c] = (uint8_t)((p23 >> 8) & 0xFF);
}

// P3 variant: also emits dp4[r][c] = (act4>0 ? W4f8[c] : 0) from registers,
// replacing P4's 64-cndmask select build (R10 hotspot).
__device__ __forceinline__ void gemm_fwd3_f8(const uint8_t (*in)[264],
                                             const uint8_t* __restrict__ Pm,
                                             const float* __restrict__ bias,
                                             const uint8_t* __restrict__ W4F8,
                                             uint8_t (*outb)[264],
                                             uint8_t (*dp4b)[264],
                                             int wave, int lane) {
  const int row16 = lane & 15, g = lane >> 4;
  const int c = row16 + 16 * wave;
  long bfr[8], afr[8];
#pragma unroll
  for (int kt = 0; kt < 8; ++kt)
    bfr[kt] = *reinterpret_cast<const long*>(Pm + (kt * 256 + c) * 32 + g * 8);
#pragma unroll
  for (int kt = 0; kt < 8; ++kt)
    afr[kt] = *reinterpret_cast<const long*>(&in[row16][kt * 32 + g * 8]);
  f32x4 acc = {0.f, 0.f, 0.f, 0.f};
#pragma unroll
  for (int kt = 0; kt < 8; ++kt)
    acc = __builtin_amdgcn_mfma_f32_16x16x32_fp8_fp8(afr[kt], bfr[kt], acc, 0, 0, 0);
  const float bv = bias[c];
  const uint8_t w4b = W4F8[c];
  const float h0 = fmaxf(fmaf(acc[0], INV_WS, bv), 0.0f);
  const float h1 = fmaxf(fmaf(acc[1], INV_WS, bv), 0.0f);
  const float h2 = fmaxf(fmaf(acc[2], INV_WS, bv), 0.0f);
  const float h3 = fmaxf(fmaf(acc[3], INV_WS, bv), 0.0f);
  const int p01 = __builtin_amdgcn_cvt_pk_fp8_f32(h0, h1, 0, false);
  const int p23 = __builtin_amdgcn_cvt_pk_fp8_f32(h2, h3, 0, false);
  outb[g * 4 + 0][c] = (uint8_t)(p01 & 0xFF);
  outb[g * 4 + 1][c] = (uint8_t)((p01 >> 8) & 0xFF);
  outb[g * 4 + 2][c] = (uint8_t)(p23 & 0xFF);
  outb[g * 4 + 3][c] = (uint8_t)((p23 >> 8) & 0xFF);
  dp4b[g * 4 + 0][c] = (h0 > 0.0f) ? w4b : (uint8_t)0;
  dp4b[g * 4 + 1][c] = (h1 > 0.0f) ? w4b : (uint8_t)0;
  dp4b[g * 4 + 2][c] = (h2 > 0.0f) ? w4b : (uint8_t)0;
  dp4b[g * 4 + 3][c] = (h3 > 0.0f) ? w4b : (uint8_t)0;
}

__device__ __forceinline__ void gemm_bwd_f8(const uint8_t (*in)[264],
                                            const uint8_t* __restrict__ Pm,
                                            const uint8_t (*mact)[264],
                                            uint8_t (*outb)[264],
                                            int wave, int lane) {
  const int row16 = lane & 15, g = lane >> 4;
  const int c = row16 + 16 * wave;
  long bfr[8], afr[8];
#pragma unroll
  for (int kt = 0; kt < 8; ++kt)
    bfr[kt] = *reinterpret_cast<const long*>(Pm + (kt * 256 + c) * 32 + g * 8);
#pragma unroll
  for (int kt = 0; kt < 8; ++kt)
    afr[kt] = *reinterpret_cast<const long*>(&in[row16][kt * 32 + g * 8]);
  f32x4 acc = {0.f, 0.f, 0.f, 0.f};
#pragma unroll
  for (int kt = 0; kt < 8; ++kt)
    acc = __builtin_amdgcn_mfma_f32_16x16x32_fp8_fp8(afr[kt], bfr[kt], acc, 0, 0, 0);
  // acc = 4096*dp_new ; store fp8 at dp scale 128 -> acc/32
  const int p01 = __builtin_amdgcn_cvt_pk_fp8_f32(acc[0] * INV_WS, acc[1] * INV_WS, 0, false);
  const int p23 = __builtin_amdgcn_cvt_pk_fp8_f32(acc[2] * INV_WS, acc[3] * INV_WS, 0, false);
  outb[g * 4 + 0][c] = mact[g * 4 + 0][c] ? (uint8_t)(p01 & 0xFF) : (uint8_t)0;
  outb[g * 4 + 1][c] = mact[g * 4 + 1][c] ? (uint8_t)((p01 >> 8) & 0xFF) : (uint8_t)0;
  outb[g * 4 + 2][c] = mact[g * 4 + 2][c] ? (uint8_t)(p23 & 0xFF) : (uint8_t)0;
  outb[g * 4 + 3][c] = mact[g * 4 + 3][c] ? (uint8_t)((p23 >> 8) & 0xFF) : (uint8_t)0;
}

// ---------------- MLP fwd + VJP eval (NOINLINE: hard codegen boundary) ------
// R9-proven: keep this outlined. Inlining it lets the scheduler hoist weight
// loads across barriers -> VGPR blowout -> scratch spill -> L2 pollution ->
// 10.5 GB HBM re-fetch (R7/R8). DO NOT inline.
__device__ __attribute__((noinline)) void mlp_eval(
    SmemT& sm, const uint8_t* __restrict__ P,
    const float* __restrict__ b0, const float* __restrict__ b1,
    const float* __restrict__ b2, const float* __restrict__ b3,
    const float* __restrict__ W4, const float* __restrict__ b4,
    float* __restrict__ ys_out, int row0, int next_s, int blk, float sqdt) {
  const int tid = threadIdx.x;
  const int wave = tid >> 6, lane = tid & 63;
  const int row16 = lane & 15, g = lane >> 4;
  const int c = row16 + 16 * wave;

  // P0: L0 fwd, bf16 MFMA (x-sensitivity: keep input layer high precision)
  {
    const uint16_t* P0F = (const uint16_t*)(P + OB_P0F);
    bf16x8 bfr[4], afr[4];
#pragma unroll
    for (int kt = 0; kt < 4; ++kt)
      bfr[kt] = *reinterpret_cast<const bf16x8*>(&P0F[(kt * 256 + c) * 32 + g * 8]);
#pragma unroll
    for (int kt = 0; kt < 4; ++kt)
      afr[kt] = *reinterpret_cast<const bf16x8*>(&sm.actI[row16][kt * 32 + g * 8]);
    const float bv = b0[c];
    f32x4 acc = {bv, bv, bv, bv};
#pragma unroll
    for (int kt = 0; kt < 4; ++kt)
      acc = __builtin_amdgcn_mfma_f32_16x16x32_bf16(afr[kt], bfr[kt], acc, 0, 0, 0);
    const float h0 = fmaxf(acc[0], 0.0f), h1 = fmaxf(acc[1], 0.0f);
    const float h2 = fmaxf(acc[2], 0.0f), h3 = fmaxf(acc[3], 0.0f);
    const int p01 = __builtin_amdgcn_cvt_pk_fp8_f32(h0, h1, 0, false);
    const int p23 = __builtin_amdgcn_cvt_pk_fp8_f32(h2, h3, 0, false);
    sm.act1[g * 4 + 0][c] = (uint8_t)(p01 & 0xFF);
    sm.act1[g * 4 + 1][c] = (uint8_t)((p01 >> 8) & 0xFF);
    sm.act1[g * 4 + 2][c] = (uint8_t)(p23 & 0xFF);
    sm.act1[g * 4 + 3][c] = (uint8_t)((p23 >> 8) & 0xFF);
  }
  __syncthreads();

  // P1-P3: fwd fp8 (P3 also emits dp4 from registers)
  gemm_fwd_f8(sm.act1, P + OB_P1F, b1, sm.act2, wave, lane);
  __syncthreads();
  gemm_fwd_f8(sm.act2, P + OB_P2F, b2, sm.act3, wave, lane);
  __syncthreads();
  gemm_fwd3_f8(sm.act3, P + OB_P3F, b3, P + OB_W4F8, sm.act4, sm.dp4, wave, lane);
  __syncthreads();

  // P4: y-reduction (wave w owns row w; act4 is fp8) + bwd3 (A = dp4 tile)
  {
    const uint32_t aw = *reinterpret_cast<const uint32_t*>(&sm.act4[wave][lane * 4]);
    float sy = __builtin_amdgcn_cvt_f32_fp8(aw, 0) * W4[lane * 4 + 0]
             + __builtin_amdgcn_cvt_f32_fp8(aw, 1) * W4[lane * 4 + 1]
             + __builtin_amdgcn_cvt_f32_fp8(aw, 2) * W4[lane * 4 + 2]
             + __builtin_amdgcn_cvt_f32_fp8(aw, 3) * W4[lane * 4 + 3];
#pragma unroll
    for (int off = 32; off >= 1; off >>= 1) sy += __shfl_xor(sy, off, 64);
    if (lane == 0) {
      const float yv = sy + b4[0];
      sm.y_s[wave] = yv;
      if (ys_out) ys_out[row0 + wave] = yv;
    }
  }
  gemm_bwd_f8(sm.dp4, P + OB_P3B, sm.act3, sm.dpA, wave, lane);
  __syncthreads();

  // P5: bwd2 ; P6: bwd1 (fp8)
  gemm_bwd_f8(sm.dpA, P + OB_P2B, sm.act2, sm.dpB, wave, lane);
  __syncthreads();
  gemm_bwd_f8(sm.dpB, P + OB_P1B, sm.act1, sm.dpA, wave, lane);
  __syncthreads();

  // P7: bwd0 on waves 0-7 (z = acc/4096); waves 8-15 next-step PRNG
  if (wave < 8) {
    const uint8_t* Pm = P + OB_P0B;
    long bfr[8], afr[8];
#pragma unroll
    for (int kt = 0; kt < 8; ++kt)
      bfr[kt] = *reinterpret_cast<const long*>(Pm + (kt * 128 + c) * 32 + g * 8);
#pragma unroll
    for (int kt = 0; kt < 8; ++kt)
      afr[kt] = *reinterpret_cast<const long*>(&sm.dpA[row16][kt * 32 + g * 8]);
    f32x4 acc = {0.f, 0.f, 0.f, 0.f};
#pragma unroll
    for (int kt = 0; kt < 8; ++kt)
      acc = __builtin_amdgcn_mfma_f32_16x16x32_fp8_fp8(afr[kt], bfr[kt], acc, 0, 0, 0);
    if (c < H_DIM) {
#pragma unroll
      for (int reg = 0; reg < 4; ++reg)
        sm.z_s[(g * 4 + reg) * H_DIM + c] = acc[reg] * INV_ZS;
    }
  } else if (next_s >= 0) {
    const uint32_t ka = sm.keyA[next_s], kb = sm.keyB[next_s];
#pragma unroll
    for (int rr = 0; rr < 2; ++rr) {
      const int r = (wave - 8) * 2 + rr;
#pragma unroll
      for (int itn = 0; itn < 2; ++itn) {
        const int h = lane + itn * 64;
        if (h < H_DIM) {
          const uint32_t f = (uint32_t)(blk * (ROWS * H_DIM) + r * H_DIM + h);
          uint32_t o0, o1;
          threefry2x32(ka, kb, 0u, f, o0, o1);
          const uint32_t bits = o0 ^ o1;
          const float fr = __uint_as_float((bits >> 9) | 0x3F800000u) - 1.0f;
          const float minv = -0.99999994f;  // nextafter(-1, 0)
          const float u = fmaxf(fr * 2.0f + minv, minv);
          const float n = 1.41421354f * erfinv_f32(u);
          sm.dw_s[r * H_DIM + h] = n * sqdt;
        }
      }
    }
  }
  __syncthreads();
}

// ---------------- main kernel ----------------
__global__ __launch_bounds__(THREADS, 4) void fbsde_kernel(
    const float* __restrict__ x0, const float* __restrict__ t0p,
    const float* __restrict__ dtp,
    const float* __restrict__ b0, const float* __restrict__ b1,
    const float* __restrict__ b2, const float* __restrict__ b3,
    const float* __restrict__ W4, const float* __restrict__ b4,
    const uint8_t* __restrict__ P, float* __restrict__ out) {
  __shared__ __align__(16) SmemT sm;

  const int tid = threadIdx.x;
  const int wave = tid >> 6, lane = tid & 63;
  const int blk = blockIdx.x;
  const int row0 = blk * ROWS;

  // ---- init ----
  if (tid < T_STEPS) {
    const uint32_t* K = (const uint32_t*)(P + OB_KEYS);
    sm.keyA[tid] = K[2 * tid];
    sm.keyB[tid] = K[2 * tid + 1];
  }
  for (int e = tid; e < ROWS * H_DIM; e += THREADS)
    sm.x_s[e] = x0[row0 * H_DIM + e];
  for (int e = tid; e < ROWS * 136; e += THREADS) {
    const int r = e / 136, cc = e - r * 136;
    uint16_t v = 0;
    if (cc >= 1 && cc <= H_DIM) v = f2bf(x0[(row0 + r) * H_DIM + cc - 1]);
    sm.actI[r][cc] = v;   // cc==0 -> t=0.0 -> bf16 0
  }
  const float t0v = t0p[0];
  const float dtv = dtp[0];
  const float sqdt = sqrtf(dtv);
  __syncthreads();

  float* const out_xfin = out;                                  // (B,H)
  float* const out_yfin = out + 409600;                         // (B,1)
  float* const out_zfin = out + 413696;                         // (B,H)
  float* const out_xs   = out + 823296;                         // (T,B,H)
  float* const out_yt   = out + 823296 + 40960000;              // (T,B,1)
  float* const out_ys   = out + 823296 + 40960000 + 409600;     // (T,B,1)

  // initial eval at t=0 (no ys write; waves 8-15 generate dW for step 0)
  mlp_eval(sm, P, b0, b1, b2, b3, W4, b4, nullptr, row0, 0, blk, sqdt);

  for (int s = 0; s < T_STEPS; ++s) {
    // ---- SDE phase: y_tilde + x-update + next actI; wave w owns row w ----
    const float tv = t0v + (float)(s + 1) * dtv;
    {
      const int base = wave * H_DIM;
      const int h0 = lane;                 // < 100 always (lane<64)
      const int h1 = lane + 64;            // valid if < 100
      const float xv0 = sm.x_s[base + h0];
      const float zv0 = sm.z_s[base + h0];
      const float dw0 = sm.dw_s[base + h0];
      float s1 = xv0 * zv0;
      float s2 = zv0 * (0.4f * xv0) * dw0;
      float xv1 = 0.f, dw1 = 0.f;
      if (h1 < H_DIM) {
        xv1 = sm.x_s[base + h1];
        const float zv1 = sm.z_s[base + h1];
        dw1 = sm.dw_s[base + h1];
        s1 += xv1 * zv1;
        s2 += zv1 * (0.4f * xv1) * dw1;
      }
#pragma unroll
      for (int off = 32; off >= 1; off >>= 1) {
        s1 += __shfl_xor(s1, off, 64);
        s2 += __shfl_xor(s2, off, 64);
      }
      if (lane == 0) {
        const float yv = sm.y_s[wave];
        const float phi = 0.05f * (yv - s1);
        out_yt[(size_t)s * B_TRAJ + row0 + wave] = yv + phi * dtv + s2;
        sm.actI[wave][0] = f2bf(tv);
      }
      {
        const float x1 = xv0 + (0.4f * xv0) * dw0;
        sm.x_s[base + h0] = x1;
        sm.actI[wave][1 + h0] = f2bf(x1);
        out_xs[(size_t)s * (B_TRAJ * H_DIM) + (size_t)(row0 + wave) * H_DIM + h0] = x1;
        if (h1 < H_DIM) {
          const float x1b = xv1 + (0.4f * xv1) * dw1;
          sm.x_s[base + h1] = x1b;
          sm.actI[wave][1 + h1] = f2bf(x1b);
          out_xs[(size_t)s * (B_TRAJ * H_DIM) + (size_t)(row0 + wave) * H_DIM + h1] = x1b;
        }
      }
    }
    __syncthreads();

    mlp_eval(sm, P, b0, b1, b2, b3, W4, b4, out_ys + (size_t)s * B_TRAJ,
             row0, (s + 1 < T_STEPS) ? s + 1 : -1, blk, sqdt);
  }

  for (int e = tid; e < ROWS * H_DIM; e += THREADS) {
    out_xfin[(size_t)row0 * H_DIM + e] = sm.x_s[e];
    out_zfin[(size_t)row0 * H_DIM + e] = sm.z_s[e];
  }
  if (tid < ROWS) out_yfin[row0 + tid] = sm.y_s[tid];
}

extern "C" void kernel_launch(void* const* d_in, const int* in_sizes, int n_in,
                              void* d_out, int out_size, void* d_ws, size_t ws_size,
                              hipStream_t stream) {
  (void)in_sizes; (void)n_in; (void)ws_size; (void)out_size;
  const float* x0 = (const float*)d_in[0];
  const float* t0 = (const float*)d_in[1];
  const float* dt = (const float*)d_in[2];
  const float* W0 = (const float*)d_in[4];
  const float* b0 = (const float*)d_in[5];
  const float* W1 = (const float*)d_in[6];
  const float* b1 = (const float*)d_in[7];
  const float* W2 = (const float*)d_in[8];
  const float* b2 = (const float*)d_in[9];
  const float* W3 = (const float*)d_in[10];
  const float* b3 = (const float*)d_in[11];
  const float* W4 = (const float*)d_in[12];
  const float* b4 = (const float*)d_in[13];
  uint8_t* P = (uint8_t*)d_ws;
  float* out = (float*)d_out;

  hipLaunchKernelGGL(pack_kernel, dim3(PACK_GRID), dim3(256), 0, stream,
                     W0, W1, W2, W3, W4, P);
  hipLaunchKernelGGL(fbsde_kernel, dim3(NBLK), dim3(THREADS), 0, stream,
                     x0, t0, dt, b0, b1, b2, b3, W4, b4, P, out);
}